// Round 1
// baseline (268.443 us; speedup 1.0000x reference)
//
#include <hip/hip_runtime.h>
#include <math.h>

// Router: x[8192,4096] fp32; Wg,Wc[64,4096]; scores=|cls*silu(gate)|, softmax,
// top-8 of scores+bias, weights = 1 + scores*extra_scale (gathered).
// Out: weights [8192,8] fp32, then indices [8192,8] written as float values.

#define T_DIM 8192
#define D_DIM 4096
#define E_DIM 64
#define N2    128      // 64 gate cols + 64 cls cols
#define MB    128      // rows per workgroup
#define BK    32       // K-tile
#define LDA   132      // padded LDS stride (128 + 4)
#define KTOP  8

// ---------------- Kernel 1: fp32 tiled GEMM, C[T,128] partials over K-slices ---
__global__ __launch_bounds__(256, 2)
void router_gemm(const float* __restrict__ x,
                 const float* __restrict__ Wg,
                 const float* __restrict__ Wc,
                 float* __restrict__ P,
                 int sliceK)
{
    __shared__ float sx[BK][LDA];   // k-major x tile  [k][m]
    __shared__ float sw[BK][LDA];   // k-major w tile  [k][n]

    const int tid = threadIdx.x;
    const int mb  = blockIdx.x;
    const int ks  = blockIdx.y;

    // staging mapping: 2 threads per row, each loads 4 float4 (16 floats of k)
    const int r2 = tid >> 1;        // 0..127: x-row within tile / w output col
    const int kq = tid & 1;         // which 16-float k-half

    const int k0 = ks * sliceK;

    const float4* xp = (const float4*)(x + (size_t)(mb * MB + r2) * D_DIM + k0 + kq * 16);
    const float*  wrow = (r2 < E_DIM) ? (Wg + (size_t)r2 * D_DIM)
                                      : (Wc + (size_t)(r2 - E_DIM) * D_DIM);
    const float4* wp = (const float4*)(wrow + k0 + kq * 16);

    float4 rx[4], rw[4];
    #pragma unroll
    for (int q = 0; q < 4; ++q) { rx[q] = xp[q]; rw[q] = wp[q]; }

    float acc[8][8];
    #pragma unroll
    for (int i = 0; i < 8; ++i)
        #pragma unroll
        for (int j = 0; j < 8; ++j) acc[i][j] = 0.f;

    const int tm8 = (tid & 15) * 8;   // row block of this thread
    const int tn8 = (tid >> 4) * 8;   // col block of this thread
    const int NS  = sliceK / BK;

    for (int s = 0; s < NS; ++s) {
        // registers -> LDS (transpose to k-major); conflict-free by construction
        #pragma unroll
        for (int q = 0; q < 4; ++q) {
            const int k = kq * 16 + q * 4;
            sx[k+0][r2] = rx[q].x; sx[k+1][r2] = rx[q].y;
            sx[k+2][r2] = rx[q].z; sx[k+3][r2] = rx[q].w;
            sw[k+0][r2] = rw[q].x; sw[k+1][r2] = rw[q].y;
            sw[k+2][r2] = rw[q].z; sw[k+3][r2] = rw[q].w;
        }
        __syncthreads();

        // prefetch next tile into registers; latency hidden by the 2048-FMA body
        if (s + 1 < NS) {
            xp += 8; wp += 8;
            #pragma unroll
            for (int q = 0; q < 4; ++q) { rx[q] = xp[q]; rw[q] = wp[q]; }
        }

        #pragma unroll
        for (int kk = 0; kk < BK; ++kk) {
            const float4 a0 = *(const float4*)&sx[kk][tm8];
            const float4 a1 = *(const float4*)&sx[kk][tm8 + 4];
            const float4 b0 = *(const float4*)&sw[kk][tn8];
            const float4 b1 = *(const float4*)&sw[kk][tn8 + 4];
            const float a[8] = {a0.x,a0.y,a0.z,a0.w,a1.x,a1.y,a1.z,a1.w};
            const float b[8] = {b0.x,b0.y,b0.z,b0.w,b1.x,b1.y,b1.z,b1.w};
            #pragma unroll
            for (int i = 0; i < 8; ++i)
                #pragma unroll
                for (int j = 0; j < 8; ++j)
                    acc[i][j] = fmaf(a[i], b[j], acc[i][j]);
        }
        __syncthreads();
    }

    // store partial C tile: P[ks][row][n]
    float* Pr = P + ((size_t)ks * T_DIM + (size_t)mb * MB + tm8) * N2 + tn8;
    #pragma unroll
    for (int i = 0; i < 8; ++i) {
        const float4 s0 = make_float4(acc[i][0], acc[i][1], acc[i][2], acc[i][3]);
        const float4 s1 = make_float4(acc[i][4], acc[i][5], acc[i][6], acc[i][7]);
        *(float4*)&Pr[(size_t)i * N2]     = s0;
        *(float4*)&Pr[(size_t)i * N2 + 4] = s1;
    }
}

// ---------------- Kernel 2: reduce slices + silu/abs/softmax + biased top-8 ----
__global__ __launch_bounds__(256)
void router_topk(const float* __restrict__ P,
                 const float* __restrict__ scale,
                 const float* __restrict__ bias,
                 float* __restrict__ out,
                 int ksplit)
{
    const int lane = threadIdx.x & 63;   // expert id
    const int wid  = threadIdx.x >> 6;
    const int row  = blockIdx.x * 4 + wid;

    float g = 0.f, c = 0.f;
    for (int ks = 0; ks < ksplit; ++ks) {
        const float* p = P + ((size_t)ks * T_DIM + row) * N2;
        g += p[lane];
        c += p[E_DIM + lane];
    }
    const float sg = g / (1.f + expf(-g));   // silu(gate)
    const float v  = fabsf(c * sg);          // score pre-softmax

    // fp32 softmax across the 64 lanes
    float m = v;
    #pragma unroll
    for (int off = 32; off >= 1; off >>= 1) m = fmaxf(m, __shfl_xor(m, off));
    const float e = expf(v - m);
    float Z = e;
    #pragma unroll
    for (int off = 32; off >= 1; off >>= 1) Z += __shfl_xor(Z, off);
    const float s = e / Z;

    const float sc  = scale[lane];
    float cur = s + bias[lane];              // selection key

    float myw = 0.f; int myi = 0;
    #pragma unroll
    for (int j = 0; j < KTOP; ++j) {
        // wave argmax, ties -> lowest index (matches jax.lax.top_k)
        float bv = cur; int bi = lane;
        #pragma unroll
        for (int off = 32; off >= 1; off >>= 1) {
            const float ov = __shfl_xor(bv, off);
            const int   oi = __shfl_xor(bi, off);
            if (ov > bv || (ov == bv && oi < bi)) { bv = ov; bi = oi; }
        }
        const float s_bi  = __shfl(s,  bi);
        const float sc_bi = __shfl(sc, bi);
        const float w = 1.f + s_bi * sc_bi;  // "original" gathered at bi
        if (lane == j)  { myw = w; myi = bi; }
        if (lane == bi) cur = -INFINITY;
    }

    if (lane < KTOP) {
        out[(size_t)row * KTOP + lane] = myw;
        out[(size_t)T_DIM * KTOP + (size_t)row * KTOP + lane] = (float)myi;
    }
}

extern "C" void kernel_launch(void* const* d_in, const int* in_sizes, int n_in,
                              void* d_out, int out_size, void* d_ws, size_t ws_size,
                              hipStream_t stream)
{
    const float* x  = (const float*)d_in[0];
    const float* Wg = (const float*)d_in[1];
    const float* Wc = (const float*)d_in[2];
    const float* sc = (const float*)d_in[3];
    const float* bs = (const float*)d_in[4];
    float* out = (float*)d_out;
    float* P   = (float*)d_ws;

    // K-split partials need ksplit * 4 MB of workspace; degrade gracefully.
    int ksplit = 8;
    const size_t per = (size_t)T_DIM * N2 * sizeof(float);   // 4 MB
    while (ksplit > 1 && (size_t)ksplit * per > ws_size) ksplit >>= 1;
    const int sliceK = D_DIM / ksplit;

    dim3 g1(T_DIM / MB, ksplit);
    router_gemm<<<g1, 256, 0, stream>>>(x, Wg, Wc, P, sliceK);
    router_topk<<<T_DIM / 4, 256, 0, stream>>>(P, sc, bs, out, ksplit);
}